// Round 1
// baseline (6111.355 us; speedup 1.0000x reference)
//
#include <hip/hip_runtime.h>
#include <cfloat>
#include <cstddef>

#define NKEYS  100000
#define SPLITS 64

// ---------------- generic tiled GEMM: C = act(A@W + bias) ----------------
// A [M,K], W [K,N], bias [N], C [M,N]. M%64==0, N%64==0, K%16==0 (all true here).
__global__ __launch_bounds__(256) void gemm_bias_act(
    const float* __restrict__ A, const float* __restrict__ W,
    const float* __restrict__ bias, float* __restrict__ C,
    int M, int N, int K, int do_gelu)
{
    __shared__ float sA[16][64];   // sA[kk][m]
    __shared__ float sW[16][64];   // sW[kk][n]
    const int tid = threadIdx.x;
    const int tx = tid & 15, ty = tid >> 4;
    const int m0 = blockIdx.y * 64, n0 = blockIdx.x * 64;
    const int arow = tid >> 2, akk = (tid & 3) << 2;
    const int wrow = tid >> 4, wcol = (tid & 15) << 2;
    float acc[4][4] = {};
    for (int k0 = 0; k0 < K; k0 += 16) {
        float4 av = *(const float4*)(A + (size_t)(m0 + arow) * K + k0 + akk);
        float4 wv = *(const float4*)(W + (size_t)(k0 + wrow) * N + n0 + wcol);
        __syncthreads();
        sA[akk + 0][arow] = av.x;
        sA[akk + 1][arow] = av.y;
        sA[akk + 2][arow] = av.z;
        sA[akk + 3][arow] = av.w;
        *(float4*)&sW[wrow][wcol] = wv;
        __syncthreads();
        #pragma unroll
        for (int kk = 0; kk < 16; ++kk) {
            float4 a = *(const float4*)&sA[kk][ty << 2];
            float4 w = *(const float4*)&sW[kk][tx << 2];
            float av4[4] = {a.x, a.y, a.z, a.w};
            float wv4[4] = {w.x, w.y, w.z, w.w};
            #pragma unroll
            for (int i = 0; i < 4; ++i)
                #pragma unroll
                for (int j = 0; j < 4; ++j)
                    acc[i][j] = fmaf(av4[i], wv4[j], acc[i][j]);
        }
    }
    float4 bv = *(const float4*)(bias + n0 + (tx << 2));
    float bias4[4] = {bv.x, bv.y, bv.z, bv.w};
    #pragma unroll
    for (int i = 0; i < 4; ++i) {
        float o[4];
        #pragma unroll
        for (int j = 0; j < 4; ++j) {
            float v = acc[i][j] + bias4[j];
            if (do_gelu) v = 0.5f * v * (1.0f + erff(v * 0.70710678118654752f));
            o[j] = v;
        }
        float4 ov = {o[0], o[1], o[2], o[3]};
        *(float4*)(C + (size_t)(m0 + (ty << 2) + i) * N + n0 + (tx << 2)) = ov;
    }
}

// ---------------- row LayerNorm (in-place), C in {256,512}, one block/row ----
__global__ __launch_bounds__(256) void ln_rows(
    float* __restrict__ X, const float* __restrict__ g, const float* __restrict__ b, int C)
{
    const int row = blockIdx.x;
    const int tid = threadIdx.x;
    float* xr = X + (size_t)row * C;
    float v0 = xr[tid];
    float v1 = (C > 256) ? xr[tid + 256] : 0.0f;
    float s = v0 + v1;
    float ss = v0 * v0 + v1 * v1;
    #pragma unroll
    for (int off = 32; off > 0; off >>= 1) {
        s  += __shfl_xor(s, off);
        ss += __shfl_xor(ss, off);
    }
    __shared__ float red[10];
    const int wave = tid >> 6, lane = tid & 63;
    if (lane == 0) { red[wave] = s; red[wave + 4] = ss; }
    __syncthreads();
    if (tid == 0) {
        float S  = red[0] + red[1] + red[2] + red[3];
        float SS = red[4] + red[5] + red[6] + red[7];
        float m = S / C;
        float var = SS / C - m * m;
        red[8] = m;
        red[9] = 1.0f / sqrtf(var + 1e-5f);
    }
    __syncthreads();
    float m = red[8], inv = red[9];
    xr[tid] = (v0 - m) * inv * g[tid] + b[tid];
    if (C > 256) xr[tid + 256] = (v1 - m) * inv * g[tid + 256] + b[tid + 256];
}

// ---------------- squared row norms, 256-col rows, 4 rows/block --------------
__global__ __launch_bounds__(256) void row_sqnorm(
    const float* __restrict__ X, float* __restrict__ out, int R)
{
    const int row = blockIdx.x * 4 + (threadIdx.x >> 6);
    const int lane = threadIdx.x & 63;
    if (row >= R) return;
    float4 v = *(const float4*)(X + (size_t)row * 256 + (lane << 2));
    float ss = v.x * v.x + v.y * v.y + v.z * v.z + v.w * v.w;
    #pragma unroll
    for (int off = 32; off > 0; off >>= 1) ss += __shfl_xor(ss, off);
    if (lane == 0) out[row] = ss;
}

// ---------------- top-5 insertion (sorted descending by score) ---------------
__device__ __forceinline__ void topk5_insert(float (&s)[5], int (&ix)[5], float v, int vi) {
    if (v > s[4]) {
        s[4] = v; ix[4] = vi;
        #pragma unroll
        for (int i = 4; i > 0; --i) {
            if (s[i] > s[i - 1]) {
                float ts = s[i]; s[i] = s[i - 1]; s[i - 1] = ts;
                int ti = ix[i]; ix[i] = ix[i - 1]; ix[i - 1] = ti;
            }
        }
    }
}

// ---------------- fused distance + per-block top-5 ---------------------------
// score = q.k - 0.5*|k|^2  (max score == min distance; q^2 added at merge)
// block: 32 queries x one key-split; thread: 2 queries x 4 keys per 64-key chunk
__global__ __launch_bounds__(256) void dist_topk(
    const float* __restrict__ qc, const float* __restrict__ keys,
    const float* __restrict__ k2, float* __restrict__ cand_s, int* __restrict__ cand_i)
{
    __shared__ float sQ[32][260];   // stride 260: 16B-aligned rows, conflict-free
    __shared__ float mS[32][8][5];
    __shared__ int   mI[32][8][5];
    const int tid = threadIdx.x;
    const int q0 = blockIdx.y * 32;
    const int split = blockIdx.x;
    const int SPLIT = (NKEYS + SPLITS - 1) / SPLITS;   // 1563
    const int kstart = split * SPLIT;
    const int kend = min(kstart + SPLIT, NKEYS);
    {
        const int r = tid >> 3;
        const int c = (tid & 7) << 5;
        const float* src = qc + (size_t)(q0 + r) * 256 + c;
        #pragma unroll
        for (int j = 0; j < 8; ++j)
            *(float4*)&sQ[r][c + (j << 2)] = *(const float4*)(src + (j << 2));
    }
    __syncthreads();
    const int tx = tid & 15, ty = tid >> 4;
    const int r0 = ty << 1;
    float bs[2][5]; int bi[2][5];
    #pragma unroll
    for (int i = 0; i < 2; ++i)
        #pragma unroll
        for (int j = 0; j < 5; ++j) { bs[i][j] = -FLT_MAX; bi[i][j] = 0; }

    for (int kb = kstart; kb < kend; kb += 64) {
        float acc0[4] = {}, acc1[4] = {};
        int key[4]; const float* kp[4];
        #pragma unroll
        for (int j = 0; j < 4; ++j) {
            key[j] = kb + (tx << 2) + j;
            int kcl = key[j] < NKEYS ? key[j] : NKEYS - 1;
            kp[j] = keys + (size_t)kcl * 256;
        }
        #pragma unroll 4
        for (int kk = 0; kk < 256; kk += 4) {
            float4 qa = *(const float4*)&sQ[r0][kk];
            float4 qb = *(const float4*)&sQ[r0 + 1][kk];
            #pragma unroll
            for (int j = 0; j < 4; ++j) {
                float4 kv = *(const float4*)(kp[j] + kk);
                acc0[j] = fmaf(qa.x, kv.x, acc0[j]);
                acc0[j] = fmaf(qa.y, kv.y, acc0[j]);
                acc0[j] = fmaf(qa.z, kv.z, acc0[j]);
                acc0[j] = fmaf(qa.w, kv.w, acc0[j]);
                acc1[j] = fmaf(qb.x, kv.x, acc1[j]);
                acc1[j] = fmaf(qb.y, kv.y, acc1[j]);
                acc1[j] = fmaf(qb.z, kv.z, acc1[j]);
                acc1[j] = fmaf(qb.w, kv.w, acc1[j]);
            }
        }
        #pragma unroll
        for (int j = 0; j < 4; ++j) {
            bool ok = key[j] < kend;
            float h  = ok ? k2[key[j]] : 0.0f;
            float s0 = ok ? fmaf(-0.5f, h, acc0[j]) : -FLT_MAX;
            float s1 = ok ? fmaf(-0.5f, h, acc1[j]) : -FLT_MAX;
            topk5_insert(bs[0], bi[0], s0, key[j]);
            topk5_insert(bs[1], bi[1], s1, key[j]);
        }
    }
    // merge lane pairs (tx, tx^1) in-register to halve the LDS merge buffer
    #pragma unroll
    for (int i = 0; i < 2; ++i) {
        float os[5]; int oi[5];
        #pragma unroll
        for (int j = 0; j < 5; ++j) {
            os[j] = __shfl_xor(bs[i][j], 1);
            oi[j] = __shfl_xor(bi[i][j], 1);
        }
        #pragma unroll
        for (int j = 0; j < 5; ++j) topk5_insert(bs[i], bi[i], os[j], oi[j]);
    }
    if ((tx & 1) == 0) {
        #pragma unroll
        for (int i = 0; i < 2; ++i)
            #pragma unroll
            for (int j = 0; j < 5; ++j) { mS[r0 + i][tx >> 1][j] = bs[i][j]; mI[r0 + i][tx >> 1][j] = bi[i][j]; }
    }
    __syncthreads();
    if (tid < 32) {
        float fs[5]; int fi[5];
        #pragma unroll
        for (int j = 0; j < 5; ++j) { fs[j] = -FLT_MAX; fi[j] = 0; }
        for (int t = 0; t < 8; ++t)
            #pragma unroll
            for (int j = 0; j < 5; ++j) topk5_insert(fs, fi, mS[tid][t][j], mI[tid][t][j]);
        const size_t base = ((size_t)(q0 + tid) * SPLITS + split) * 5;
        #pragma unroll
        for (int j = 0; j < 5; ++j) { cand_s[base + j] = fs[j]; cand_i[base + j] = fi[j]; }
    }
}

// ---------------- global merge: 320 candidates -> top-5, weights, confidence --
__global__ __launch_bounds__(64) void merge_topk(
    const float* __restrict__ cand_s, const int* __restrict__ cand_i,
    const float* __restrict__ q2, float* __restrict__ w5, int* __restrict__ idx5,
    float* __restrict__ conf)
{
    const int q = blockIdx.x * 64 + threadIdx.x;
    float fs[5]; int fi[5];
    #pragma unroll
    for (int j = 0; j < 5; ++j) { fs[j] = -FLT_MAX; fi[j] = 0; }
    const float* cs = cand_s + (size_t)q * (SPLITS * 5);
    const int*   ci = cand_i + (size_t)q * (SPLITS * 5);
    for (int t = 0; t < SPLITS * 5; ++t) topk5_insert(fs, fi, cs[t], ci[t]);
    const float qq = q2[q];
    float w[5], d0 = 0.0f, Wsum = 0.0f;
    #pragma unroll
    for (int j = 0; j < 5; ++j) {
        float d = fmaxf(fmaf(-2.0f, fs[j], qq), 0.0f);   // d = q2 + k2 - 2 q.k, clamped
        if (j == 0) d0 = d;                               // scores desc => d asc
        w[j] = 1.0f / (d + 1e-6f);
        Wsum += w[j];
    }
    #pragma unroll
    for (int j = 0; j < 5; ++j) { w5[q * 5 + j] = w[j] / Wsum; idx5[q * 5 + j] = fi[j]; }
    conf[q] = 1.0f / (d0 + 1e-6f);
}

// ---------------- gather values_c rows for decompress ------------------------
__global__ __launch_bounds__(256) void gather_rows(
    const float* __restrict__ values, const int* __restrict__ idx5, float* __restrict__ X0)
{
    const int row = blockIdx.x;          // 0..5119 = q*5+i
    const int idx = idx5[row];
    X0[(size_t)row * 256 + threadIdx.x] = values[(size_t)idx * 256 + threadIdx.x];
}

// ---------------- weighted combine of 5 decompressed h2 rows -> z [1024,512] --
__global__ __launch_bounds__(128) void combine_weighted(
    const float* __restrict__ h2d, const float* __restrict__ w5, float* __restrict__ z)
{
    const int q = blockIdx.x;
    const int t = threadIdx.x;
    float4 acc = {0.0f, 0.0f, 0.0f, 0.0f};
    #pragma unroll
    for (int i = 0; i < 5; ++i) {
        float w = w5[q * 5 + i];
        float4 v = *(const float4*)(h2d + ((size_t)q * 5 + i) * 512 + (t << 2));
        acc.x = fmaf(w, v.x, acc.x);
        acc.y = fmaf(w, v.y, acc.y);
        acc.z = fmaf(w, v.z, acc.z);
        acc.w = fmaf(w, v.w, acc.w);
    }
    *(float4*)(z + (size_t)q * 512 + (t << 2)) = acc;
}

// ---------------- workspace layout (floats) ----------------------------------
// phase 1-3:  h1@0(512K) h2@512K(256K) qc@768K(256K) q2@1M(1K) k2@1.025M(98K)
//             cand_s@1149952(320K) cand_i@1477632(320K)
// phase 4:    X0@0(1.25M) t1@1310720(1.25M) t2@2621440(2.5M) z@1310720(overlays dead t1)
// persistent: w5@5242880(5K) idx5@5248000(5K)   total 21.0 MB
#define OFF_H1 0
#define OFF_H2 524288
#define OFF_QC 786432
#define OFF_Q2 1048576
#define OFF_K2 1049600
#define OFF_CS 1149952
#define OFF_CI 1477632
#define OFF_X0 0
#define OFF_T1 1310720
#define OFF_T2 2621440
#define OFF_Z  1310720
#define OFF_W5 5242880
#define OFF_I5 5248000

extern "C" void kernel_launch(void* const* d_in, const int* in_sizes, int n_in,
                              void* d_out, int out_size, void* d_ws, size_t ws_size,
                              hipStream_t stream) {
    const float* query  = (const float*)d_in[0];
    const float* keys   = (const float*)d_in[1];
    const float* values = (const float*)d_in[2];
    const float* cW1 = (const float*)d_in[3];  const float* cb1 = (const float*)d_in[4];
    const float* cg1 = (const float*)d_in[5];  const float* cB1 = (const float*)d_in[6];
    const float* cW2 = (const float*)d_in[7];  const float* cb2 = (const float*)d_in[8];
    const float* cg2 = (const float*)d_in[9];  const float* cB2 = (const float*)d_in[10];
    const float* cW3 = (const float*)d_in[11]; const float* cb3 = (const float*)d_in[12];
    const float* dW1 = (const float*)d_in[13]; const float* db1 = (const float*)d_in[14];
    const float* dg1 = (const float*)d_in[15]; const float* dB1 = (const float*)d_in[16];
    const float* dW2 = (const float*)d_in[17]; const float* db2 = (const float*)d_in[18];
    const float* dg2 = (const float*)d_in[19]; const float* dB2 = (const float*)d_in[20];
    const float* dW3 = (const float*)d_in[21]; const float* db3 = (const float*)d_in[22];
    float* out = (float*)d_out;
    float* ws  = (float*)d_ws;

    float* h1 = ws + OFF_H1;  float* h2 = ws + OFF_H2;  float* qc = ws + OFF_QC;
    float* q2 = ws + OFF_Q2;  float* k2 = ws + OFF_K2;
    float* cand_s = ws + OFF_CS;  int* cand_i = (int*)(ws + OFF_CI);
    float* X0 = ws + OFF_X0;  float* t1 = ws + OFF_T1;  float* t2 = ws + OFF_T2;
    float* z  = ws + OFF_Z;
    float* w5 = ws + OFF_W5;  int* idx5 = (int*)(ws + OFF_I5);

    // ---- compress: q_c = MLP(query) ----
    gemm_bias_act<<<dim3(8, 16),  256, 0, stream>>>(query, cW1, cb1, h1, 1024, 512, 1024, 1);
    ln_rows<<<1024, 256, 0, stream>>>(h1, cg1, cB1, 512);
    gemm_bias_act<<<dim3(4, 16),  256, 0, stream>>>(h1, cW2, cb2, h2, 1024, 256, 512, 1);
    ln_rows<<<1024, 256, 0, stream>>>(h2, cg2, cB2, 256);
    gemm_bias_act<<<dim3(4, 16),  256, 0, stream>>>(h2, cW3, cb3, qc, 1024, 256, 256, 0);
    row_sqnorm<<<256,   256, 0, stream>>>(qc,   q2, 1024);
    row_sqnorm<<<25000, 256, 0, stream>>>(keys, k2, NKEYS);

    // ---- fused distances + top-5 ----
    dist_topk<<<dim3(SPLITS, 32), 256, 0, stream>>>(qc, keys, k2, cand_s, cand_i);
    merge_topk<<<16, 64, 0, stream>>>(cand_s, cand_i, q2, w5, idx5, out + 1024 * 1024);

    // ---- decompress 5120 gathered rows, combine, final linear into d_out ----
    gather_rows<<<5120, 256, 0, stream>>>(values, idx5, X0);
    gemm_bias_act<<<dim3(4, 80),  256, 0, stream>>>(X0, dW1, db1, t1, 5120, 256, 256, 1);
    ln_rows<<<5120, 256, 0, stream>>>(t1, dg1, dB1, 256);
    gemm_bias_act<<<dim3(8, 80),  256, 0, stream>>>(t1, dW2, db2, t2, 5120, 512, 256, 1);
    ln_rows<<<5120, 256, 0, stream>>>(t2, dg2, dB2, 512);
    combine_weighted<<<1024, 128, 0, stream>>>(t2, w5, z);
    gemm_bias_act<<<dim3(16, 16), 256, 0, stream>>>(z, dW3, db3, out, 1024, 1024, 512, 0);
}

// Round 2
// 906.283 us; speedup vs baseline: 6.7433x; 6.7433x over previous
//
#include <hip/hip_runtime.h>
#include <cfloat>
#include <cstddef>

typedef __attribute__((ext_vector_type(8))) short bf16x8;
typedef __attribute__((ext_vector_type(4))) float f32x4;

#define NKEYS    100000
#define SPLITS   61
#define SPLITLEN 1664
#define NKP      (SPLITS * SPLITLEN)   /* 101504 padded key rows */

// ---------------- helpers ----------------------------------------------------
__device__ __forceinline__ unsigned short f2bf(float x) {
    unsigned int u = __float_as_uint(x);
    unsigned int r = (u + 0x7fffu + ((u >> 16) & 1u)) >> 16;
    return (unsigned short)r;
}

__device__ __forceinline__ void async16(void* lds, const void* g) {
    __builtin_amdgcn_global_load_lds(
        (const __attribute__((address_space(1))) unsigned int*)g,
        (__attribute__((address_space(3))) unsigned int*)lds, 16, 0, 0);
}

__device__ __forceinline__ void topk5_insert(float (&s)[5], int (&ix)[5], float v, int vi) {
    if (v > s[4]) {
        s[4] = v; ix[4] = vi;
        #pragma unroll
        for (int i = 4; i > 0; --i) {
            if (s[i] > s[i - 1]) {
                float ts = s[i]; s[i] = s[i - 1]; s[i - 1] = ts;
                int ti = ix[i]; ix[i] = ix[i - 1]; ix[i - 1] = ti;
            }
        }
    }
}

// ---------------- generic tiled GEMM: C = act(A@W + bias) --------------------
__global__ __launch_bounds__(256) void gemm_bias_act(
    const float* __restrict__ A, const float* __restrict__ W,
    const float* __restrict__ bias, float* __restrict__ C,
    int M, int N, int K, int do_gelu)
{
    __shared__ float sA[16][64];
    __shared__ float sW[16][64];
    const int tid = threadIdx.x;
    const int tx = tid & 15, ty = tid >> 4;
    const int m0 = blockIdx.y * 64, n0 = blockIdx.x * 64;
    const int arow = tid >> 2, akk = (tid & 3) << 2;
    const int wrow = tid >> 4, wcol = (tid & 15) << 2;
    float acc[4][4] = {};
    for (int k0 = 0; k0 < K; k0 += 16) {
        float4 av = *(const float4*)(A + (size_t)(m0 + arow) * K + k0 + akk);
        float4 wv = *(const float4*)(W + (size_t)(k0 + wrow) * N + n0 + wcol);
        __syncthreads();
        sA[akk + 0][arow] = av.x;
        sA[akk + 1][arow] = av.y;
        sA[akk + 2][arow] = av.z;
        sA[akk + 3][arow] = av.w;
        *(float4*)&sW[wrow][wcol] = wv;
        __syncthreads();
        #pragma unroll
        for (int kk = 0; kk < 16; ++kk) {
            float4 a = *(const float4*)&sA[kk][ty << 2];
            float4 w = *(const float4*)&sW[kk][tx << 2];
            float av4[4] = {a.x, a.y, a.z, a.w};
            float wv4[4] = {w.x, w.y, w.z, w.w};
            #pragma unroll
            for (int i = 0; i < 4; ++i)
                #pragma unroll
                for (int j = 0; j < 4; ++j)
                    acc[i][j] = fmaf(av4[i], wv4[j], acc[i][j]);
        }
    }
    float4 bv = *(const float4*)(bias + n0 + (tx << 2));
    float bias4[4] = {bv.x, bv.y, bv.z, bv.w};
    #pragma unroll
    for (int i = 0; i < 4; ++i) {
        float o[4];
        #pragma unroll
        for (int j = 0; j < 4; ++j) {
            float v = acc[i][j] + bias4[j];
            if (do_gelu) v = 0.5f * v * (1.0f + erff(v * 0.70710678118654752f));
            o[j] = v;
        }
        float4 ov = {o[0], o[1], o[2], o[3]};
        *(float4*)(C + (size_t)(m0 + (ty << 2) + i) * N + n0 + (tx << 2)) = ov;
    }
}

// ---------------- row LayerNorm (in-place), C in {256,512} -------------------
__global__ __launch_bounds__(256) void ln_rows(
    float* __restrict__ X, const float* __restrict__ g, const float* __restrict__ b, int C)
{
    const int row = blockIdx.x;
    const int tid = threadIdx.x;
    float* xr = X + (size_t)row * C;
    float v0 = xr[tid];
    float v1 = (C > 256) ? xr[tid + 256] : 0.0f;
    float s = v0 + v1;
    float ss = v0 * v0 + v1 * v1;
    #pragma unroll
    for (int off = 32; off > 0; off >>= 1) {
        s  += __shfl_xor(s, off);
        ss += __shfl_xor(ss, off);
    }
    __shared__ float red[10];
    const int wave = tid >> 6, lane = tid & 63;
    if (lane == 0) { red[wave] = s; red[wave + 4] = ss; }
    __syncthreads();
    if (tid == 0) {
        float S  = red[0] + red[1] + red[2] + red[3];
        float SS = red[4] + red[5] + red[6] + red[7];
        float m = S / C;
        float var = SS / C - m * m;
        red[8] = m;
        red[9] = 1.0f / sqrtf(var + 1e-5f);
    }
    __syncthreads();
    float m = red[8], inv = red[9];
    xr[tid] = (v0 - m) * inv * g[tid] + b[tid];
    if (C > 256) xr[tid + 256] = (v1 - m) * inv * g[tid + 256] + b[tid + 256];
}

// ---------------- fp32 rows -> bf16 rows + squared norms (256-wide rows) -----
__global__ __launch_bounds__(256) void prep_rows(
    const float* __restrict__ X, unsigned short* __restrict__ xh,
    float* __restrict__ x2, int nvalid, int ntot)
{
    const int row = blockIdx.x * 4 + (threadIdx.x >> 6);
    const int lane = threadIdx.x & 63;
    if (row >= ntot) return;
    if (row < nvalid) {
        float4 v = *(const float4*)(X + (size_t)row * 256 + (lane << 2));
        float ss = v.x * v.x + v.y * v.y + v.z * v.z + v.w * v.w;
        #pragma unroll
        for (int off = 32; off > 0; off >>= 1) ss += __shfl_xor(ss, off);
        ushort4 h;
        h.x = f2bf(v.x); h.y = f2bf(v.y); h.z = f2bf(v.z); h.w = f2bf(v.w);
        *(ushort4*)(xh + (size_t)row * 256 + (lane << 2)) = h;
        if (lane == 0) x2[row] = ss;
    } else {
        ushort4 z = {0, 0, 0, 0};
        *(ushort4*)(xh + (size_t)row * 256 + (lane << 2)) = z;
        if (lane == 0) x2[row] = 0.0f;
    }
}

// ---------------- MFMA distance + fused per-split top-5 ----------------------
// S = Q @ K^T via 16x16x32 bf16 MFMA. Block = 64 queries (4 waves x 16) x one
// key split; chunk = 128 keys. score = q.k - 0.5*|k|^2 (exact fp32 k2).
// B staged via global_load_lds in frag order (lane-sequential ds_read_b128).
__global__ __launch_bounds__(256) void dist_topk_mfma(
    const unsigned short* __restrict__ khi, const unsigned short* __restrict__ qhi,
    const float* __restrict__ k2, float* __restrict__ cand_s, int* __restrict__ cand_i)
{
    __shared__ unsigned short sB[8192];   // 16 KB: 128 keys x 64 dims (one K-step)
    const int tid = threadIdx.x;
    const int lane = tid & 63;
    const int wv = tid >> 6;
    const int split = blockIdx.x;
    const int q0 = blockIdx.y * 64 + wv * 16;
    const int kstart = split * SPLITLEN;

    // A fragments: 16 queries x full K=256, 8 steps of K=32, in registers
    bf16x8 aF[8];
    {
        const unsigned short* qb = qhi + (((size_t)(q0 + (lane & 15))) << 8) + ((lane >> 4) << 3);
        #pragma unroll
        for (int s = 0; s < 8; ++s)
            aF[s] = *(const bf16x8*)(qb + s * 32);
    }

    float bs[4][5]; int bi[4][5];
    #pragma unroll
    for (int r = 0; r < 4; ++r)
        #pragma unroll
        for (int j = 0; j < 5; ++j) { bs[r][j] = -FLT_MAX; bi[r][j] = 0; }

    for (int kb = kstart; kb < kstart + SPLITLEN; kb += 128) {
        f32x4 acc[8];
        #pragma unroll
        for (int t = 0; t < 8; ++t) acc[t] = (f32x4){0.f, 0.f, 0.f, 0.f};
        #pragma unroll
        for (int s = 0; s < 4; ++s) {          // K-steps of 64 dims
            __syncthreads();
            #pragma unroll
            for (int i = 0; i < 4; ++i) {      // stage 16 KB, frag-ordered
                int e = i * 256 + tid;
                int h = e >> 9, t = (e >> 6) & 7, L = e & 63;
                const unsigned short* src = khi
                    + (((size_t)(kb + t * 16 + (L & 15))) << 8)
                    + (s << 6) + (h << 5) + ((L >> 4) << 3);
                async16(&sB[(size_t)e << 3], src);
            }
            __syncthreads();                   // drains vmcnt before reads
            #pragma unroll
            for (int h = 0; h < 2; ++h) {
                #pragma unroll
                for (int t = 0; t < 8; ++t) {
                    bf16x8 b = *(const bf16x8*)&sB[((((h << 3) + t) << 6) | lane) << 3];
                    acc[t] = __builtin_amdgcn_mfma_f32_16x16x32_bf16(
                        aF[(s << 1) + h], b, acc[t], 0, 0, 0);
                }
            }
        }
        // fused epilogue: scores + running per-lane top-5 (4 queries/lane)
        #pragma unroll
        for (int t = 0; t < 8; ++t) {
            int key = kb + t * 16 + (lane & 15);
            float k2v = k2[key];
            bool valid = key < NKEYS;
            #pragma unroll
            for (int r = 0; r < 4; ++r) {
                float sc = valid ? fmaf(-0.5f, k2v, acc[t][r]) : -FLT_MAX;
                topk5_insert(bs[r], bi[r], sc, key);
            }
        }
    }
    // butterfly merge across the 16 lanes of each quad (same 4 queries)
    #pragma unroll
    for (int m = 1; m <= 8; m <<= 1) {
        #pragma unroll
        for (int r = 0; r < 4; ++r) {
            float os[5]; int oi[5];
            #pragma unroll
            for (int j = 0; j < 5; ++j) {
                os[j] = __shfl_xor(bs[r][j], m);
                oi[j] = __shfl_xor(bi[r][j], m);
            }
            #pragma unroll
            for (int j = 0; j < 5; ++j) topk5_insert(bs[r], bi[r], os[j], oi[j]);
        }
    }
    if ((lane & 15) == 0) {
        #pragma unroll
        for (int r = 0; r < 4; ++r) {
            int q = q0 + ((lane >> 4) << 2) + r;
            size_t base = ((size_t)q * SPLITS + split) * 5;
            #pragma unroll
            for (int j = 0; j < 5; ++j) { cand_s[base + j] = bs[r][j]; cand_i[base + j] = bi[r][j]; }
        }
    }
}

// ---------------- merge per-split candidates -> approx top-8 per query -------
__global__ __launch_bounds__(256) void merge8(
    const float* __restrict__ cand_s, const int* __restrict__ cand_i,
    int* __restrict__ idx8)
{
    const int q = blockIdx.x * 256 + threadIdx.x;
    float fs[8]; int fi[8];
    #pragma unroll
    for (int j = 0; j < 8; ++j) { fs[j] = -FLT_MAX; fi[j] = 0; }
    const float* cs = cand_s + (size_t)q * (SPLITS * 5);
    const int*   ci = cand_i + (size_t)q * (SPLITS * 5);
    for (int t = 0; t < SPLITS * 5; ++t) {
        float v = cs[t];
        if (v > fs[7]) {
            fs[7] = v; fi[7] = ci[t];
            #pragma unroll
            for (int j = 7; j > 0; --j) {
                if (fs[j] > fs[j - 1]) {
                    float ts = fs[j]; fs[j] = fs[j - 1]; fs[j - 1] = ts;
                    int ti = fi[j]; fi[j] = fi[j - 1]; fi[j - 1] = ti;
                }
            }
        }
    }
    #pragma unroll
    for (int j = 0; j < 8; ++j) idx8[q * 8 + j] = fi[j];
}

// ---------------- exact fp32 rerank of top-8 -> top-5, weights, confidence ---
__global__ __launch_bounds__(256) void rerank(
    const float* __restrict__ qc, const float* __restrict__ keys,
    const float* __restrict__ k2, const float* __restrict__ q2,
    const int* __restrict__ idx8, float* __restrict__ w5,
    int* __restrict__ idx5, float* __restrict__ conf)
{
    const int q = blockIdx.x * 4 + (threadIdx.x >> 6);
    const int lane = threadIdx.x & 63;
    float4 qv = *(const float4*)(qc + (size_t)q * 256 + (lane << 2));
    float dot[8]; int cidx[8];
    #pragma unroll
    for (int c = 0; c < 8; ++c) {
        cidx[c] = idx8[q * 8 + c];
        float4 kv = *(const float4*)(keys + (size_t)cidx[c] * 256 + (lane << 2));
        dot[c] = qv.x * kv.x + qv.y * kv.y + qv.z * kv.z + qv.w * kv.w;
    }
    #pragma unroll
    for (int c = 0; c < 8; ++c)
        #pragma unroll
        for (int off = 32; off > 0; off >>= 1) dot[c] += __shfl_xor(dot[c], off);
    if (lane == 0) {
        float d[8]; int di[8];
        const float qq = q2[q];
        #pragma unroll
        for (int c = 0; c < 8; ++c) {
            d[c] = fmaxf(qq + k2[cidx[c]] - 2.0f * dot[c], 0.0f);
            di[c] = cidx[c];
        }
        #pragma unroll
        for (int a = 1; a < 8; ++a) {           // insertion sort ascending
            float dv = d[a]; int iv = di[a]; int b = a;
            while (b > 0 && d[b - 1] > dv) { d[b] = d[b - 1]; di[b] = di[b - 1]; --b; }
            d[b] = dv; di[b] = iv;
        }
        float w[5], sum = 0.0f;
        #pragma unroll
        for (int j = 0; j < 5; ++j) { w[j] = 1.0f / (d[j] + 1e-6f); sum += w[j]; }
        #pragma unroll
        for (int j = 0; j < 5; ++j) { w5[q * 5 + j] = w[j] / sum; idx5[q * 5 + j] = di[j]; }
        conf[q] = 1.0f / (d[0] + 1e-6f);
    }
}

// ---------------- gather values_c rows for decompress ------------------------
__global__ __launch_bounds__(256) void gather_rows(
    const float* __restrict__ values, const int* __restrict__ idx5, float* __restrict__ X0)
{
    const int row = blockIdx.x;
    const int idx = idx5[row];
    X0[(size_t)row * 256 + threadIdx.x] = values[(size_t)idx * 256 + threadIdx.x];
}

// ---------------- weighted combine of 5 decompressed h2 rows -----------------
__global__ __launch_bounds__(128) void combine_weighted(
    const float* __restrict__ h2d, const float* __restrict__ w5, float* __restrict__ z)
{
    const int q = blockIdx.x;
    const int t = threadIdx.x;
    float4 acc = {0.0f, 0.0f, 0.0f, 0.0f};
    #pragma unroll
    for (int i = 0; i < 5; ++i) {
        float w = w5[q * 5 + i];
        float4 v = *(const float4*)(h2d + ((size_t)q * 5 + i) * 512 + (t << 2));
        acc.x = fmaf(w, v.x, acc.x);
        acc.y = fmaf(w, v.y, acc.y);
        acc.z = fmaf(w, v.z, acc.z);
        acc.w = fmaf(w, v.w, acc.w);
    }
    *(float4*)(z + (size_t)q * 512 + (t << 2)) = acc;
}

// ---------------- workspace layout (float offsets), ~83 MB -------------------
#define OFF_KHI 0               /* NKP x 256 bf16 = 12992512 floats */
#define OFF_K2  12992512
#define OFF_QHI 13094016
#define OFF_Q2  13225088
#define OFF_CS  13226112        /* 1024 x 305 */
#define OFF_CI  13538432
#define OFF_I8  13850752
#define OFF_H1  13858944
#define OFF_H2  14383232
#define OFF_QC  14645376
#define OFF_X0  14907520
#define OFF_T1  16218240
#define OFF_T2  17528960
#define OFF_Z   20150400
#define OFF_W5  20674688
#define OFF_I5  20679808

extern "C" void kernel_launch(void* const* d_in, const int* in_sizes, int n_in,
                              void* d_out, int out_size, void* d_ws, size_t ws_size,
                              hipStream_t stream) {
    const float* query  = (const float*)d_in[0];
    const float* keys   = (const float*)d_in[1];
    const float* values = (const float*)d_in[2];
    const float* cW1 = (const float*)d_in[3];  const float* cb1 = (const float*)d_in[4];
    const float* cg1 = (const float*)d_in[5];  const float* cB1 = (const float*)d_in[6];
    const float* cW2 = (const float*)d_in[7];  const float* cb2 = (const float*)d_in[8];
    const float* cg2 = (const float*)d_in[9];  const float* cB2 = (const float*)d_in[10];
    const float* cW3 = (const float*)d_in[11]; const float* cb3 = (const float*)d_in[12];
    const float* dW1 = (const float*)d_in[13]; const float* db1 = (const float*)d_in[14];
    const float* dg1 = (const float*)d_in[15]; const float* dB1 = (const float*)d_in[16];
    const float* dW2 = (const float*)d_in[17]; const float* db2 = (const float*)d_in[18];
    const float* dg2 = (const float*)d_in[19]; const float* dB2 = (const float*)d_in[20];
    const float* dW3 = (const float*)d_in[21]; const float* db3 = (const float*)d_in[22];
    float* out = (float*)d_out;
    float* ws  = (float*)d_ws;

    unsigned short* khi = (unsigned short*)(ws + OFF_KHI);
    float* k2 = ws + OFF_K2;
    unsigned short* qhi = (unsigned short*)(ws + OFF_QHI);
    float* q2 = ws + OFF_Q2;
    float* cand_s = ws + OFF_CS;  int* cand_i = (int*)(ws + OFF_CI);
    int* idx8 = (int*)(ws + OFF_I8);
    float* h1 = ws + OFF_H1;  float* h2 = ws + OFF_H2;  float* qc = ws + OFF_QC;
    float* X0 = ws + OFF_X0;  float* t1 = ws + OFF_T1;  float* t2 = ws + OFF_T2;
    float* z  = ws + OFF_Z;
    float* w5 = ws + OFF_W5;  int* idx5 = (int*)(ws + OFF_I5);

    // keys -> bf16 + exact k2 (pad rows zeroed)
    prep_rows<<<NKP / 4, 256, 0, stream>>>(keys, khi, k2, NKEYS, NKP);

    // compress: q_c = MLP(query)
    gemm_bias_act<<<dim3(8, 16),  256, 0, stream>>>(query, cW1, cb1, h1, 1024, 512, 1024, 1);
    ln_rows<<<1024, 256, 0, stream>>>(h1, cg1, cB1, 512);
    gemm_bias_act<<<dim3(4, 16),  256, 0, stream>>>(h1, cW2, cb2, h2, 1024, 256, 512, 1);
    ln_rows<<<1024, 256, 0, stream>>>(h2, cg2, cB2, 256);
    gemm_bias_act<<<dim3(4, 16),  256, 0, stream>>>(h2, cW3, cb3, qc, 1024, 256, 256, 0);
    prep_rows<<<256, 256, 0, stream>>>(qc, qhi, q2, 1024, 1024);

    // approx distances via MFMA + fused top-5, then exact rerank of top-8
    dist_topk_mfma<<<dim3(SPLITS, 16), 256, 0, stream>>>(khi, qhi, k2, cand_s, cand_i);
    merge8<<<4, 256, 0, stream>>>(cand_s, cand_i, idx8);
    rerank<<<256, 256, 0, stream>>>(qc, keys, k2, q2, idx8, w5, idx5, out + 1024 * 1024);

    // decompress 5120 gathered rows, combine, final linear into d_out
    gather_rows<<<5120, 256, 0, stream>>>(values, idx5, X0);
    gemm_bias_act<<<dim3(4, 80),  256, 0, stream>>>(X0, dW1, db1, t1, 5120, 256, 256, 1);
    ln_rows<<<5120, 256, 0, stream>>>(t1, dg1, dB1, 256);
    gemm_bias_act<<<dim3(8, 80),  256, 0, stream>>>(t1, dW2, db2, t2, 5120, 512, 256, 1);
    ln_rows<<<5120, 256, 0, stream>>>(t2, dg2, dB2, 512);
    combine_weighted<<<1024, 128, 0, stream>>>(t2, w5, z);
    gemm_bias_act<<<dim3(16, 16), 256, 0, stream>>>(z, dW3, db3, out, 1024, 1024, 512, 0);
}